// Round 3
// baseline (1262.971 us; speedup 1.0000x reference)
//
#include <hip/hip_runtime.h>
#include <math.h>
#include <float.h>

// ---------------------------------------------------------------------------
// GCN on MI355X. N=50000 nodes, E=1.6M edges, feature widths 128 -> 64 (x8) -> 4.
// Strategy: build dst-sorted CSR once per call (counting sort), then each layer
// is GEMM (dense, LDS-staged W) + per-node gather aggregation (wave per node,
// lane per feature). Final layer reassociated to (A x) @ W3. Softmax over the
// node axis via encoded atomicMax + atomicAdd.
// ---------------------------------------------------------------------------

// ---------------- degree / CSR build ----------------

__global__ __launch_bounds__(256) void k_count(const int* __restrict__ dst,
                                               unsigned* __restrict__ deg, int E) {
    int e = blockIdx.x * 256 + threadIdx.x;
    if (e < E) atomicAdd(&deg[dst[e]], 1u);
}

__global__ __launch_bounds__(256) void k_dinv(const unsigned* __restrict__ deg,
                                              float* __restrict__ dinv, int n) {
    int i = blockIdx.x * 256 + threadIdx.x;
    if (i < n) dinv[i] = rsqrtf(1.0f + (float)deg[i]);
}

// hierarchical exclusive scan of deg -> row_start (chunk = 256 per block)
__global__ __launch_bounds__(256) void k_scan1(const unsigned* __restrict__ deg,
                                               int* __restrict__ row_start,
                                               unsigned* __restrict__ bsum, int n) {
    __shared__ unsigned t[256];
    int i = blockIdx.x * 256 + threadIdx.x;
    unsigned v = (i < n) ? deg[i] : 0u;
    t[threadIdx.x] = v;
    __syncthreads();
    #pragma unroll
    for (int off = 1; off < 256; off <<= 1) {
        unsigned u = (threadIdx.x >= (unsigned)off) ? t[threadIdx.x - off] : 0u;
        __syncthreads();
        t[threadIdx.x] += u;
        __syncthreads();
    }
    if (i < n) row_start[i] = (int)(t[threadIdx.x] - v);  // block-local exclusive
    if (threadIdx.x == 255) bsum[blockIdx.x] = t[255];
}

__global__ __launch_bounds__(256) void k_scan2(unsigned* __restrict__ bsum,
                                               int* __restrict__ row_start,
                                               int nb, int n) {
    __shared__ unsigned t[256];
    unsigned v = (threadIdx.x < (unsigned)nb) ? bsum[threadIdx.x] : 0u;
    t[threadIdx.x] = v;
    __syncthreads();
    #pragma unroll
    for (int off = 1; off < 256; off <<= 1) {
        unsigned u = (threadIdx.x >= (unsigned)off) ? t[threadIdx.x - off] : 0u;
        __syncthreads();
        t[threadIdx.x] += u;
        __syncthreads();
    }
    if (threadIdx.x < (unsigned)nb) bsum[threadIdx.x] = t[threadIdx.x] - v;  // exclusive
    if (threadIdx.x == 255) row_start[n] = (int)t[255];
}

__global__ __launch_bounds__(256) void k_scan3(int* __restrict__ row_start,
                                               const unsigned* __restrict__ bsum, int n) {
    int i = blockIdx.x * 256 + threadIdx.x;
    if (i < n) row_start[i] += (int)bsum[blockIdx.x];
}

__global__ __launch_bounds__(256) void k_fill(const int* __restrict__ src,
                                              const int* __restrict__ dst,
                                              const int* __restrict__ row_start,
                                              unsigned* __restrict__ cursor,
                                              const float* __restrict__ dinv,
                                              int* __restrict__ csr_src,
                                              float* __restrict__ csr_w, int E) {
    int e = blockIdx.x * 256 + threadIdx.x;
    if (e >= E) return;
    int s = src[e], d = dst[e];
    unsigned pos = atomicAdd(&cursor[d], 1u);
    int slot = row_start[d] + (int)pos;
    csr_src[slot] = s;
    csr_w[slot] = dinv[s] * dinv[d];
}

// ---------------- dense GEMM: h[n,64] = x[n,FIN] @ W[FIN,64] ----------------

template <int FIN>
__global__ __launch_bounds__(256) void k_gemm64(const float* __restrict__ x,
                                                const float* __restrict__ W,
                                                float* __restrict__ h, int n) {
    __shared__ float Wl[FIN * 64];
    for (int idx = threadIdx.x; idx < FIN * 64; idx += 256) Wl[idx] = W[idx];
    __syncthreads();
    int wave = threadIdx.x >> 6, lane = threadIdx.x & 63;
    int base = blockIdx.x * 64 + wave * 16;
    for (int it = 0; it < 16; ++it) {
        int i = base + it;
        if (i < n) {
            const float4* xr = (const float4*)(x + (size_t)i * FIN);
            float acc = 0.f;
            #pragma unroll
            for (int k4 = 0; k4 < FIN / 4; ++k4) {
                float4 v = xr[k4];
                acc += v.x * Wl[(k4 * 4 + 0) * 64 + lane];
                acc += v.y * Wl[(k4 * 4 + 1) * 64 + lane];
                acc += v.z * Wl[(k4 * 4 + 2) * 64 + lane];
                acc += v.w * Wl[(k4 * 4 + 3) * 64 + lane];
            }
            h[(size_t)i * 64 + lane] = acc;
        }
    }
}

// small GEMM: z[n,4] = a[n,64] @ W[64,4] + b
__global__ __launch_bounds__(256) void k_gemm4(const float* __restrict__ a,
                                               const float* __restrict__ W,
                                               const float* __restrict__ b,
                                               float4* __restrict__ z, int n) {
    __shared__ float Wl[256];
    __shared__ float bl[4];
    for (int idx = threadIdx.x; idx < 256; idx += 256) Wl[idx] = W[idx];
    if (threadIdx.x < 4) bl[threadIdx.x] = b[threadIdx.x];
    __syncthreads();
    int i = blockIdx.x * 256 + threadIdx.x;
    if (i >= n) return;
    const float4* ar = (const float4*)(a + (size_t)i * 64);
    float a0 = bl[0], a1 = bl[1], a2 = bl[2], a3 = bl[3];
    #pragma unroll
    for (int k4 = 0; k4 < 16; ++k4) {
        float4 v = ar[k4];
        a0 += v.x * Wl[(k4 * 4 + 0) * 4 + 0] + v.y * Wl[(k4 * 4 + 1) * 4 + 0] +
              v.z * Wl[(k4 * 4 + 2) * 4 + 0] + v.w * Wl[(k4 * 4 + 3) * 4 + 0];
        a1 += v.x * Wl[(k4 * 4 + 0) * 4 + 1] + v.y * Wl[(k4 * 4 + 1) * 4 + 1] +
              v.z * Wl[(k4 * 4 + 2) * 4 + 1] + v.w * Wl[(k4 * 4 + 3) * 4 + 1];
        a2 += v.x * Wl[(k4 * 4 + 0) * 4 + 2] + v.y * Wl[(k4 * 4 + 1) * 4 + 2] +
              v.z * Wl[(k4 * 4 + 2) * 4 + 2] + v.w * Wl[(k4 * 4 + 3) * 4 + 2];
        a3 += v.x * Wl[(k4 * 4 + 0) * 4 + 3] + v.y * Wl[(k4 * 4 + 1) * 4 + 3] +
              v.z * Wl[(k4 * 4 + 2) * 4 + 3] + v.w * Wl[(k4 * 4 + 3) * 4 + 3];
    }
    z[i] = make_float4(a0, a1, a2, a3);
}

// ---------------- aggregation: out = A_norm * h (+bias, relu) ----------------
// one wave per node, one lane per feature (F=64)

template <bool RELU, bool BIAS>
__global__ __launch_bounds__(256) void k_agg64(const float* __restrict__ h,
                                               const float* __restrict__ dinv,
                                               const int* __restrict__ row_start,
                                               const int* __restrict__ csr_src,
                                               const float* __restrict__ csr_w,
                                               const float* __restrict__ bias,
                                               float* __restrict__ out, int n) {
    int gw = (int)((blockIdx.x * 256 + threadIdx.x) >> 6);
    int lane = threadIdx.x & 63;
    if (gw >= n) return;
    float di = dinv[gw];
    float acc = h[(size_t)gw * 64 + lane] * di * di;  // self-loop term
    int s = row_start[gw], e = row_start[gw + 1];
    int slot = s;
    for (; slot + 4 <= e; slot += 4) {
        int s0 = csr_src[slot], s1 = csr_src[slot + 1];
        int s2 = csr_src[slot + 2], s3 = csr_src[slot + 3];
        float w0 = csr_w[slot], w1 = csr_w[slot + 1];
        float w2 = csr_w[slot + 2], w3 = csr_w[slot + 3];
        float v0 = h[(size_t)s0 * 64 + lane];
        float v1 = h[(size_t)s1 * 64 + lane];
        float v2 = h[(size_t)s2 * 64 + lane];
        float v3 = h[(size_t)s3 * 64 + lane];
        acc += v0 * w0; acc += v1 * w1; acc += v2 * w2; acc += v3 * w3;
    }
    for (; slot < e; ++slot)
        acc += h[(size_t)csr_src[slot] * 64 + lane] * csr_w[slot];
    if (BIAS) acc += bias[lane];
    if (RELU) acc = fmaxf(acc, 0.f);
    out[(size_t)gw * 64 + lane] = acc;
}

// ---------------- softmax over node axis (per column, C=4) ----------------

__device__ inline unsigned encf(float f) {
    unsigned u = __float_as_uint(f);
    return (u & 0x80000000u) ? ~u : (u | 0x80000000u);
}
__device__ inline float decf(unsigned e) {
    return (e & 0x80000000u) ? __uint_as_float(e & 0x7FFFFFFFu) : __uint_as_float(~e);
}

__global__ __launch_bounds__(256) void k_max(const float4* __restrict__ z,
                                             unsigned* __restrict__ gmax, int n) {
    float m0 = -FLT_MAX, m1 = -FLT_MAX, m2 = -FLT_MAX, m3 = -FLT_MAX;
    for (int i = blockIdx.x * 256 + threadIdx.x; i < n; i += gridDim.x * 256) {
        float4 v = z[i];
        m0 = fmaxf(m0, v.x); m1 = fmaxf(m1, v.y);
        m2 = fmaxf(m2, v.z); m3 = fmaxf(m3, v.w);
    }
    #pragma unroll
    for (int off = 32; off; off >>= 1) {
        m0 = fmaxf(m0, __shfl_xor(m0, off));
        m1 = fmaxf(m1, __shfl_xor(m1, off));
        m2 = fmaxf(m2, __shfl_xor(m2, off));
        m3 = fmaxf(m3, __shfl_xor(m3, off));
    }
    if ((threadIdx.x & 63) == 0) {
        atomicMax(&gmax[0], encf(m0));
        atomicMax(&gmax[1], encf(m1));
        atomicMax(&gmax[2], encf(m2));
        atomicMax(&gmax[3], encf(m3));
    }
}

__global__ __launch_bounds__(256) void k_exp(const float4* __restrict__ z,
                                             float4* __restrict__ out,
                                             const unsigned* __restrict__ gmax,
                                             float* __restrict__ gsum, int n) {
    float M0 = decf(gmax[0]), M1 = decf(gmax[1]), M2 = decf(gmax[2]), M3 = decf(gmax[3]);
    float s0 = 0.f, s1 = 0.f, s2 = 0.f, s3 = 0.f;
    for (int i = blockIdx.x * 256 + threadIdx.x; i < n; i += gridDim.x * 256) {
        float4 v = z[i];
        float4 e;
        e.x = expf(v.x - M0); e.y = expf(v.y - M1);
        e.z = expf(v.z - M2); e.w = expf(v.w - M3);
        out[i] = e;
        s0 += e.x; s1 += e.y; s2 += e.z; s3 += e.w;
    }
    #pragma unroll
    for (int off = 32; off; off >>= 1) {
        s0 += __shfl_xor(s0, off);
        s1 += __shfl_xor(s1, off);
        s2 += __shfl_xor(s2, off);
        s3 += __shfl_xor(s3, off);
    }
    if ((threadIdx.x & 63) == 0) {
        atomicAdd(&gsum[0], s0);
        atomicAdd(&gsum[1], s1);
        atomicAdd(&gsum[2], s2);
        atomicAdd(&gsum[3], s3);
    }
}

__global__ __launch_bounds__(256) void k_norm(float4* __restrict__ out,
                                              const float* __restrict__ gsum, int n) {
    float r0 = 1.f / gsum[0], r1 = 1.f / gsum[1], r2 = 1.f / gsum[2], r3 = 1.f / gsum[3];
    for (int i = blockIdx.x * 256 + threadIdx.x; i < n; i += gridDim.x * 256) {
        float4 v = out[i];
        v.x *= r0; v.y *= r1; v.z *= r2; v.w *= r3;
        out[i] = v;
    }
}

// ---------------------------------------------------------------------------

extern "C" void kernel_launch(void* const* d_in, const int* in_sizes, int n_in,
                              void* d_out, int out_size, void* d_ws, size_t ws_size,
                              hipStream_t stream) {
    const float* x0 = (const float*)d_in[0];
    const int* ei = (const int*)d_in[1];
    const float* W1 = (const float*)d_in[2];
    const float* b1 = (const float*)d_in[3];
    const float* W2 = (const float*)d_in[4];
    const float* b2 = (const float*)d_in[5];
    const float* W3 = (const float*)d_in[6];
    const float* b3 = (const float*)d_in[7];

    const int n = in_sizes[0] / 128;   // 50000
    const int E = in_sizes[1] / 2;     // 1600000
    const int* src = ei;
    const int* dst = ei + E;

    char* ws = (char*)d_ws;
    size_t off = 0;
    auto alloc = [&](size_t bytes) -> void* {
        void* p = (void*)(ws + off);
        off = (off + bytes + 255) & ~(size_t)255;
        return p;
    };

    // zeroed region first (deg, cursor, gmax, gsum)
    unsigned* deg    = (unsigned*)alloc((size_t)n * 4);
    unsigned* cursor = (unsigned*)alloc((size_t)n * 4);
    unsigned* gmax   = (unsigned*)alloc(16);
    float*    gsum   = (float*)alloc(16);
    size_t zero_bytes = off;

    float* dinv      = (float*)alloc((size_t)n * 4);
    int*   row_start = (int*)alloc((size_t)(n + 1) * 4);
    unsigned* bsum   = (unsigned*)alloc(1024 * 4);
    int*   csr_src   = (int*)alloc((size_t)E * 4);
    float* csr_w     = (float*)alloc((size_t)E * 4);
    float* hbuf      = (float*)alloc((size_t)n * 64 * 4);
    float* xbuf      = (float*)alloc((size_t)n * 64 * 4);
    float4* zbuf     = (float4*)alloc((size_t)n * 16);

    hipMemsetAsync(deg, 0, zero_bytes, stream);

    const int nbE = (E + 255) / 256;
    const int nbN = (n + 255) / 256;

    // CSR build
    k_count<<<nbE, 256, 0, stream>>>(dst, deg, E);
    k_dinv<<<nbN, 256, 0, stream>>>(deg, dinv, n);
    k_scan1<<<nbN, 256, 0, stream>>>(deg, row_start, bsum, n);
    k_scan2<<<1, 256, 0, stream>>>(bsum, row_start, nbN, n);
    k_scan3<<<nbN, 256, 0, stream>>>(row_start, bsum, n);
    k_fill<<<nbE, 256, 0, stream>>>(src, dst, row_start, cursor, dinv, csr_src, csr_w, E);

    const int nbG = (n + 63) / 64;        // gemm blocks (64 nodes/block)
    const int nbA = (n * 64 + 255) / 256; // agg blocks (wave per node)

    // layer 1: 128 -> 64
    k_gemm64<128><<<nbG, 256, 0, stream>>>(x0, W1, hbuf, n);
    k_agg64<true, true><<<nbA, 256, 0, stream>>>(hbuf, dinv, row_start, csr_src, csr_w, b1, xbuf, n);

    // layers 2..8: 64 -> 64, shared W2
    for (int l = 0; l < 7; ++l) {
        k_gemm64<64><<<nbG, 256, 0, stream>>>(xbuf, W2, hbuf, n);
        k_agg64<true, true><<<nbA, 256, 0, stream>>>(hbuf, dinv, row_start, csr_src, csr_w, b2, xbuf, n);
    }

    // layer 9 (reassociated): a = A x ; z = a @ W3 + b3
    k_agg64<false, false><<<nbA, 256, 0, stream>>>(xbuf, dinv, row_start, csr_src, csr_w, nullptr, hbuf, n);
    k_gemm4<<<nbN, 256, 0, stream>>>(hbuf, W3, b3, zbuf, n);

    // softmax over node axis
    k_max<<<256, 256, 0, stream>>>(zbuf, gmax, n);
    k_exp<<<256, 256, 0, stream>>>(zbuf, (float4*)d_out, gmax, gsum, n);
    k_norm<<<256, 256, 0, stream>>>((float4*)d_out, gsum, n);
}

// Round 4
// 1164.064 us; speedup vs baseline: 1.0850x; 1.0850x over previous
//
#include <hip/hip_runtime.h>
#include <math.h>
#include <float.h>

// ---------------------------------------------------------------------------
// GCN on MI355X. N=50000 nodes, E=1.6M edges, widths 128 -> 64 (x8) -> 4.
// CSR (dst-sorted, src only) built once per call. dinv factors folded into
// GEMM epilogue (hs = (xW)*dinv[row]) and agg epilogue (*dinv[d]), so the
// edge gather loop is pure adds and csr_w does not exist. Final layer:
// GEMM to 4 features first, then 4-wide gather agg. Softmax over node axis.
// ---------------------------------------------------------------------------

// ---------------- degree / CSR build ----------------

__global__ __launch_bounds__(256) void k_count(const int* __restrict__ dst,
                                               unsigned* __restrict__ deg, int E) {
    int e = blockIdx.x * 256 + threadIdx.x;
    if (e < E) atomicAdd(&deg[dst[e]], 1u);
}

__global__ __launch_bounds__(256) void k_dinv(const unsigned* __restrict__ deg,
                                              float* __restrict__ dinv, int n) {
    int i = blockIdx.x * 256 + threadIdx.x;
    if (i < n) dinv[i] = rsqrtf(1.0f + (float)deg[i]);
}

// hierarchical exclusive scan of deg -> row_start (chunk = 256 per block)
__global__ __launch_bounds__(256) void k_scan1(const unsigned* __restrict__ deg,
                                               int* __restrict__ row_start,
                                               unsigned* __restrict__ bsum, int n) {
    __shared__ unsigned t[256];
    int i = blockIdx.x * 256 + threadIdx.x;
    unsigned v = (i < n) ? deg[i] : 0u;
    t[threadIdx.x] = v;
    __syncthreads();
    #pragma unroll
    for (int off = 1; off < 256; off <<= 1) {
        unsigned u = (threadIdx.x >= (unsigned)off) ? t[threadIdx.x - off] : 0u;
        __syncthreads();
        t[threadIdx.x] += u;
        __syncthreads();
    }
    if (i < n) row_start[i] = (int)(t[threadIdx.x] - v);
    if (threadIdx.x == 255) bsum[blockIdx.x] = t[255];
}

__global__ __launch_bounds__(256) void k_scan2(unsigned* __restrict__ bsum,
                                               int* __restrict__ row_start,
                                               int nb, int n) {
    __shared__ unsigned t[256];
    unsigned v = (threadIdx.x < (unsigned)nb) ? bsum[threadIdx.x] : 0u;
    t[threadIdx.x] = v;
    __syncthreads();
    #pragma unroll
    for (int off = 1; off < 256; off <<= 1) {
        unsigned u = (threadIdx.x >= (unsigned)off) ? t[threadIdx.x - off] : 0u;
        __syncthreads();
        t[threadIdx.x] += u;
        __syncthreads();
    }
    if (threadIdx.x < (unsigned)nb) bsum[threadIdx.x] = t[threadIdx.x] - v;
    if (threadIdx.x == 255) row_start[n] = (int)t[255];
}

__global__ __launch_bounds__(256) void k_scan3(int* __restrict__ row_start,
                                               const unsigned* __restrict__ bsum, int n) {
    int i = blockIdx.x * 256 + threadIdx.x;
    if (i < n) row_start[i] += (int)bsum[blockIdx.x];
}

__global__ __launch_bounds__(256) void k_fill(const int* __restrict__ src,
                                              const int* __restrict__ dst,
                                              const int* __restrict__ row_start,
                                              unsigned* __restrict__ cursor,
                                              int* __restrict__ csr_src, int E) {
    int e = blockIdx.x * 256 + threadIdx.x;
    if (e >= E) return;
    int s = src[e], d = dst[e];
    unsigned pos = atomicAdd(&cursor[d], 1u);
    csr_src[row_start[d] + (int)pos] = s;
}

// ---------- dense GEMM: hs[i,:] = (x[i,:] @ W) * dinv[i]  (FIN -> 64) ----------

template <int FIN>
__global__ __launch_bounds__(256) void k_gemm64(const float* __restrict__ x,
                                                const float* __restrict__ W,
                                                const float* __restrict__ dinv,
                                                float* __restrict__ hs, int n) {
    __shared__ float Wl[FIN * 64];
    for (int idx = threadIdx.x; idx < FIN * 64; idx += 256) Wl[idx] = W[idx];
    __syncthreads();
    int wave = threadIdx.x >> 6, lane = threadIdx.x & 63;
    int base = blockIdx.x * 64 + wave * 16;
    for (int it = 0; it < 16; ++it) {
        int i = base + it;
        if (i < n) {
            const float4* xr = (const float4*)(x + (size_t)i * FIN);
            float acc = 0.f;
            #pragma unroll
            for (int k4 = 0; k4 < FIN / 4; ++k4) {
                float4 v = xr[k4];
                acc += v.x * Wl[(k4 * 4 + 0) * 64 + lane];
                acc += v.y * Wl[(k4 * 4 + 1) * 64 + lane];
                acc += v.z * Wl[(k4 * 4 + 2) * 64 + lane];
                acc += v.w * Wl[(k4 * 4 + 3) * 64 + lane];
            }
            hs[(size_t)i * 64 + lane] = acc * dinv[i];
        }
    }
}

// ---- small GEMM: h4[i] = (a[i,:] @ W[64,4]) * dinv[i]  (no bias here) ----
__global__ __launch_bounds__(256) void k_gemm4(const float* __restrict__ a,
                                               const float* __restrict__ W,
                                               const float* __restrict__ dinv,
                                               float4* __restrict__ h4, int n) {
    __shared__ float Wl[256];
    for (int idx = threadIdx.x; idx < 256; idx += 256) Wl[idx] = W[idx];
    __syncthreads();
    int i = blockIdx.x * 256 + threadIdx.x;
    if (i >= n) return;
    const float4* ar = (const float4*)(a + (size_t)i * 64);
    float a0 = 0.f, a1 = 0.f, a2 = 0.f, a3 = 0.f;
    #pragma unroll
    for (int k4 = 0; k4 < 16; ++k4) {
        float4 v = ar[k4];
        a0 += v.x * Wl[(k4 * 4 + 0) * 4 + 0] + v.y * Wl[(k4 * 4 + 1) * 4 + 0] +
              v.z * Wl[(k4 * 4 + 2) * 4 + 0] + v.w * Wl[(k4 * 4 + 3) * 4 + 0];
        a1 += v.x * Wl[(k4 * 4 + 0) * 4 + 1] + v.y * Wl[(k4 * 4 + 1) * 4 + 1] +
              v.z * Wl[(k4 * 4 + 2) * 4 + 1] + v.w * Wl[(k4 * 4 + 3) * 4 + 1];
        a2 += v.x * Wl[(k4 * 4 + 0) * 4 + 2] + v.y * Wl[(k4 * 4 + 1) * 4 + 2] +
              v.z * Wl[(k4 * 4 + 2) * 4 + 2] + v.w * Wl[(k4 * 4 + 3) * 4 + 2];
        a3 += v.x * Wl[(k4 * 4 + 0) * 4 + 3] + v.y * Wl[(k4 * 4 + 1) * 4 + 3] +
              v.z * Wl[(k4 * 4 + 2) * 4 + 3] + v.w * Wl[(k4 * 4 + 3) * 4 + 3];
    }
    float di = dinv[i];
    h4[i] = make_float4(a0 * di, a1 * di, a2 * di, a3 * di);
}

// ------- aggregation 64-wide: out[d,:] = relu((Σ hs[s,:] + hs[d,:])*dinv[d] + b) -------
// one wave per node, one lane per feature; inner loop is pure adds.

__global__ __launch_bounds__(256) void k_agg64(const float* __restrict__ hs,
                                               const float* __restrict__ dinv,
                                               const int* __restrict__ row_start,
                                               const int* __restrict__ csr_src,
                                               const float* __restrict__ bias,
                                               float* __restrict__ out, int n) {
    int gw = (int)((blockIdx.x * 256 + threadIdx.x) >> 6);
    int lane = threadIdx.x & 63;
    if (gw >= n) return;
    float acc = hs[(size_t)gw * 64 + lane];  // self term (prescaled)
    int s = row_start[gw], e = row_start[gw + 1];
    int slot = s;
    for (; slot + 4 <= e; slot += 4) {
        int s0 = csr_src[slot], s1 = csr_src[slot + 1];
        int s2 = csr_src[slot + 2], s3 = csr_src[slot + 3];
        float v0 = hs[(size_t)s0 * 64 + lane];
        float v1 = hs[(size_t)s1 * 64 + lane];
        float v2 = hs[(size_t)s2 * 64 + lane];
        float v3 = hs[(size_t)s3 * 64 + lane];
        acc += v0; acc += v1; acc += v2; acc += v3;
    }
    for (; slot < e; ++slot)
        acc += hs[(size_t)csr_src[slot] * 64 + lane];
    acc = acc * dinv[gw] + bias[lane];
    out[(size_t)gw * 64 + lane] = fmaxf(acc, 0.f);
}

// ------- aggregation 4-wide (final layer): z[d] = (Σ h4[s] + h4[d])*dinv[d] + b3 -------
// one thread per node; per-edge gather is a single float4 from an 800KB buffer.

__global__ __launch_bounds__(256) void k_agg4(const float4* __restrict__ h4,
                                              const float* __restrict__ dinv,
                                              const int* __restrict__ row_start,
                                              const int* __restrict__ csr_src,
                                              const float* __restrict__ b3,
                                              float4* __restrict__ z, int n) {
    int i = blockIdx.x * 256 + threadIdx.x;
    if (i >= n) return;
    float4 self = h4[i];
    float a0 = self.x, a1 = self.y, a2 = self.z, a3 = self.w;
    int s = row_start[i], e = row_start[i + 1];
    int slot = s;
    for (; slot + 4 <= e; slot += 4) {
        int s0 = csr_src[slot], s1 = csr_src[slot + 1];
        int s2 = csr_src[slot + 2], s3 = csr_src[slot + 3];
        float4 v0 = h4[s0], v1 = h4[s1], v2 = h4[s2], v3 = h4[s3];
        a0 += v0.x + v1.x + v2.x + v3.x;
        a1 += v0.y + v1.y + v2.y + v3.y;
        a2 += v0.z + v1.z + v2.z + v3.z;
        a3 += v0.w + v1.w + v2.w + v3.w;
    }
    for (; slot < e; ++slot) {
        float4 v = h4[csr_src[slot]];
        a0 += v.x; a1 += v.y; a2 += v.z; a3 += v.w;
    }
    float di = dinv[i];
    z[i] = make_float4(a0 * di + b3[0], a1 * di + b3[1],
                       a2 * di + b3[2], a3 * di + b3[3]);
}

// ---------------- softmax over node axis (per column, C=4) ----------------

__device__ inline unsigned encf(float f) {
    unsigned u = __float_as_uint(f);
    return (u & 0x80000000u) ? ~u : (u | 0x80000000u);
}
__device__ inline float decf(unsigned e) {
    return (e & 0x80000000u) ? __uint_as_float(e & 0x7FFFFFFFu) : __uint_as_float(~e);
}

__global__ __launch_bounds__(256) void k_max(const float4* __restrict__ z,
                                             unsigned* __restrict__ gmax, int n) {
    float m0 = -FLT_MAX, m1 = -FLT_MAX, m2 = -FLT_MAX, m3 = -FLT_MAX;
    for (int i = blockIdx.x * 256 + threadIdx.x; i < n; i += gridDim.x * 256) {
        float4 v = z[i];
        m0 = fmaxf(m0, v.x); m1 = fmaxf(m1, v.y);
        m2 = fmaxf(m2, v.z); m3 = fmaxf(m3, v.w);
    }
    #pragma unroll
    for (int off = 32; off; off >>= 1) {
        m0 = fmaxf(m0, __shfl_xor(m0, off));
        m1 = fmaxf(m1, __shfl_xor(m1, off));
        m2 = fmaxf(m2, __shfl_xor(m2, off));
        m3 = fmaxf(m3, __shfl_xor(m3, off));
    }
    if ((threadIdx.x & 63) == 0) {
        atomicMax(&gmax[0], encf(m0));
        atomicMax(&gmax[1], encf(m1));
        atomicMax(&gmax[2], encf(m2));
        atomicMax(&gmax[3], encf(m3));
    }
}

__global__ __launch_bounds__(256) void k_exp(const float4* __restrict__ z,
                                             float4* __restrict__ out,
                                             const unsigned* __restrict__ gmax,
                                             float* __restrict__ gsum, int n) {
    float M0 = decf(gmax[0]), M1 = decf(gmax[1]), M2 = decf(gmax[2]), M3 = decf(gmax[3]);
    float s0 = 0.f, s1 = 0.f, s2 = 0.f, s3 = 0.f;
    for (int i = blockIdx.x * 256 + threadIdx.x; i < n; i += gridDim.x * 256) {
        float4 v = z[i];
        float4 e;
        e.x = expf(v.x - M0); e.y = expf(v.y - M1);
        e.z = expf(v.z - M2); e.w = expf(v.w - M3);
        out[i] = e;
        s0 += e.x; s1 += e.y; s2 += e.z; s3 += e.w;
    }
    #pragma unroll
    for (int off = 32; off; off >>= 1) {
        s0 += __shfl_xor(s0, off);
        s1 += __shfl_xor(s1, off);
        s2 += __shfl_xor(s2, off);
        s3 += __shfl_xor(s3, off);
    }
    if ((threadIdx.x & 63) == 0) {
        atomicAdd(&gsum[0], s0);
        atomicAdd(&gsum[1], s1);
        atomicAdd(&gsum[2], s2);
        atomicAdd(&gsum[3], s3);
    }
}

__global__ __launch_bounds__(256) void k_norm(float4* __restrict__ out,
                                              const float* __restrict__ gsum, int n) {
    float r0 = 1.f / gsum[0], r1 = 1.f / gsum[1], r2 = 1.f / gsum[2], r3 = 1.f / gsum[3];
    for (int i = blockIdx.x * 256 + threadIdx.x; i < n; i += gridDim.x * 256) {
        float4 v = out[i];
        v.x *= r0; v.y *= r1; v.z *= r2; v.w *= r3;
        out[i] = v;
    }
}

// ---------------------------------------------------------------------------

extern "C" void kernel_launch(void* const* d_in, const int* in_sizes, int n_in,
                              void* d_out, int out_size, void* d_ws, size_t ws_size,
                              hipStream_t stream) {
    const float* x0 = (const float*)d_in[0];
    const int* ei = (const int*)d_in[1];
    const float* W1 = (const float*)d_in[2];
    const float* b1 = (const float*)d_in[3];
    const float* W2 = (const float*)d_in[4];
    const float* b2 = (const float*)d_in[5];
    const float* W3 = (const float*)d_in[6];
    const float* b3 = (const float*)d_in[7];

    const int n = in_sizes[0] / 128;   // 50000
    const int E = in_sizes[1] / 2;     // 1600000
    const int* src = ei;
    const int* dst = ei + E;

    char* ws = (char*)d_ws;
    size_t off = 0;
    auto alloc = [&](size_t bytes) -> void* {
        void* p = (void*)(ws + off);
        off = (off + bytes + 255) & ~(size_t)255;
        return p;
    };

    // zeroed region first (deg, cursor, gmax, gsum)
    unsigned* deg    = (unsigned*)alloc((size_t)n * 4);
    unsigned* cursor = (unsigned*)alloc((size_t)n * 4);
    unsigned* gmax   = (unsigned*)alloc(16);
    float*    gsum   = (float*)alloc(16);
    size_t zero_bytes = off;

    float* dinv      = (float*)alloc((size_t)n * 4);
    int*   row_start = (int*)alloc((size_t)(n + 1) * 4);
    unsigned* bsum   = (unsigned*)alloc(1024 * 4);
    int*   csr_src   = (int*)alloc((size_t)E * 4);
    float* hbuf      = (float*)alloc((size_t)n * 64 * 4);
    float* xbuf      = (float*)alloc((size_t)n * 64 * 4);
    float4* h4buf    = (float4*)alloc((size_t)n * 16);
    float4* zbuf     = (float4*)alloc((size_t)n * 16);

    hipMemsetAsync(deg, 0, zero_bytes, stream);

    const int nbE = (E + 255) / 256;
    const int nbN = (n + 255) / 256;

    // CSR build
    k_count<<<nbE, 256, 0, stream>>>(dst, deg, E);
    k_dinv<<<nbN, 256, 0, stream>>>(deg, dinv, n);
    k_scan1<<<nbN, 256, 0, stream>>>(deg, row_start, bsum, n);
    k_scan2<<<1, 256, 0, stream>>>(bsum, row_start, nbN, n);
    k_scan3<<<nbN, 256, 0, stream>>>(row_start, bsum, n);
    k_fill<<<nbE, 256, 0, stream>>>(src, dst, row_start, cursor, csr_src, E);

    const int nbG = (n + 63) / 64;        // gemm blocks (64 nodes/block)
    const int nbA = (n * 64 + 255) / 256; // agg blocks (wave per node)

    // layer 1: 128 -> 64
    k_gemm64<128><<<nbG, 256, 0, stream>>>(x0, W1, dinv, hbuf, n);
    k_agg64<<<nbA, 256, 0, stream>>>(hbuf, dinv, row_start, csr_src, b1, xbuf, n);

    // layers 2..8: 64 -> 64, shared W2
    for (int l = 0; l < 7; ++l) {
        k_gemm64<64><<<nbG, 256, 0, stream>>>(xbuf, W2, dinv, hbuf, n);
        k_agg64<<<nbA, 256, 0, stream>>>(hbuf, dinv, row_start, csr_src, b2, xbuf, n);
    }

    // layer 9: gemm to 4 features first (A(xW3) == (Ax)W3), then 4-wide agg
    k_gemm4<<<nbN, 256, 0, stream>>>(xbuf, W3, dinv, h4buf, n);
    k_agg4<<<nbN, 256, 0, stream>>>(h4buf, dinv, row_start, csr_src, b3, zbuf, n);

    // softmax over node axis
    k_max<<<256, 256, 0, stream>>>(zbuf, gmax, n);
    k_exp<<<256, 256, 0, stream>>>(zbuf, (float4*)d_out, gmax, gsum, n);
    k_norm<<<256, 256, 0, stream>>>((float4*)d_out, gsum, n);
}

// Round 6
// 985.833 us; speedup vs baseline: 1.2811x; 1.1808x over previous
//
#include <hip/hip_runtime.h>
#include <hip/hip_fp16.h>
#include <math.h>
#include <float.h>

// ---------------------------------------------------------------------------
// GCN on MI355X. N=50000, E=1.6M, widths 128 -> 64 (x8) -> 4.
// CSR (dst-sorted, src only) built per call. dinv folded into GEMM epilogue
// and agg epilogue. Activations/hs stored as fp16 (fp32 accumulate) to halve
// gather bytes in the edge aggregation (the dominant cost). Final layer:
// GEMM to 4 features then 4-wide agg. Softmax over node axis.
// ---------------------------------------------------------------------------

// ---------------- degree / CSR build ----------------

__global__ __launch_bounds__(256) void k_count(const int* __restrict__ dst,
                                               unsigned* __restrict__ deg, int E) {
    int e = blockIdx.x * 256 + threadIdx.x;
    if (e < E) atomicAdd(&deg[dst[e]], 1u);
}

__global__ __launch_bounds__(256) void k_dinv(const unsigned* __restrict__ deg,
                                              float* __restrict__ dinv, int n) {
    int i = blockIdx.x * 256 + threadIdx.x;
    if (i < n) dinv[i] = rsqrtf(1.0f + (float)deg[i]);
}

__global__ __launch_bounds__(256) void k_scan1(const unsigned* __restrict__ deg,
                                               int* __restrict__ row_start,
                                               unsigned* __restrict__ bsum, int n) {
    __shared__ unsigned t[256];
    int i = blockIdx.x * 256 + threadIdx.x;
    unsigned v = (i < n) ? deg[i] : 0u;
    t[threadIdx.x] = v;
    __syncthreads();
    #pragma unroll
    for (int off = 1; off < 256; off <<= 1) {
        unsigned u = (threadIdx.x >= (unsigned)off) ? t[threadIdx.x - off] : 0u;
        __syncthreads();
        t[threadIdx.x] += u;
        __syncthreads();
    }
    if (i < n) row_start[i] = (int)(t[threadIdx.x] - v);
    if (threadIdx.x == 255) bsum[blockIdx.x] = t[255];
}

__global__ __launch_bounds__(256) void k_scan2(unsigned* __restrict__ bsum,
                                               int* __restrict__ row_start,
                                               int nb, int n) {
    __shared__ unsigned t[256];
    unsigned v = (threadIdx.x < (unsigned)nb) ? bsum[threadIdx.x] : 0u;
    t[threadIdx.x] = v;
    __syncthreads();
    #pragma unroll
    for (int off = 1; off < 256; off <<= 1) {
        unsigned u = (threadIdx.x >= (unsigned)off) ? t[threadIdx.x - off] : 0u;
        __syncthreads();
        t[threadIdx.x] += u;
        __syncthreads();
    }
    if (threadIdx.x < (unsigned)nb) bsum[threadIdx.x] = t[threadIdx.x] - v;
    if (threadIdx.x == 255) row_start[n] = (int)t[255];
}

__global__ __launch_bounds__(256) void k_scan3(int* __restrict__ row_start,
                                               const unsigned* __restrict__ bsum, int n) {
    int i = blockIdx.x * 256 + threadIdx.x;
    if (i < n) row_start[i] += (int)bsum[blockIdx.x];
}

__global__ __launch_bounds__(256) void k_fill(const int* __restrict__ src,
                                              const int* __restrict__ dst,
                                              const int* __restrict__ row_start,
                                              unsigned* __restrict__ cursor,
                                              int* __restrict__ csr_src, int E) {
    int e = blockIdx.x * 256 + threadIdx.x;
    if (e >= E) return;
    int s = src[e], d = dst[e];
    unsigned pos = atomicAdd(&cursor[d], 1u);
    csr_src[row_start[d] + (int)pos] = s;
}

// ---- GEMM layer1: hs[i,:] = half((x[i,:128] @ W) * dinv[i]) ----

__global__ __launch_bounds__(256) void k_gemm64_f32(const float* __restrict__ x,
                                                    const float* __restrict__ W,
                                                    const float* __restrict__ dinv,
                                                    __half* __restrict__ hs, int n) {
    __shared__ float Wl[128 * 64];
    for (int idx = threadIdx.x; idx < 128 * 64; idx += 256) Wl[idx] = W[idx];
    __syncthreads();
    int wave = threadIdx.x >> 6, lane = threadIdx.x & 63;
    int base = blockIdx.x * 64 + wave * 16;
    for (int it = 0; it < 16; ++it) {
        int i = base + it;
        if (i < n) {
            const float4* xr = (const float4*)(x + (size_t)i * 128);
            float acc = 0.f;
            #pragma unroll
            for (int k4 = 0; k4 < 32; ++k4) {
                float4 v = xr[k4];
                acc += v.x * Wl[(k4 * 4 + 0) * 64 + lane];
                acc += v.y * Wl[(k4 * 4 + 1) * 64 + lane];
                acc += v.z * Wl[(k4 * 4 + 2) * 64 + lane];
                acc += v.w * Wl[(k4 * 4 + 3) * 64 + lane];
            }
            hs[(size_t)i * 64 + lane] = __float2half(acc * dinv[i]);
        }
    }
}

// ---- GEMM layers 2..8: hs[i,:] = half((xh[i,:64] @ W) * dinv[i]) ----

__global__ __launch_bounds__(256) void k_gemm64_f16(const __half* __restrict__ xh,
                                                    const float* __restrict__ W,
                                                    const float* __restrict__ dinv,
                                                    __half* __restrict__ hs, int n) {
    __shared__ float Wl[64 * 64];
    for (int idx = threadIdx.x; idx < 64 * 64; idx += 256) Wl[idx] = W[idx];
    __syncthreads();
    int wave = threadIdx.x >> 6, lane = threadIdx.x & 63;
    int base = blockIdx.x * 64 + wave * 16;
    for (int it = 0; it < 16; ++it) {
        int i = base + it;
        if (i < n) {
            const __half2* xr = (const __half2*)(xh + (size_t)i * 64);
            float acc = 0.f;
            #pragma unroll
            for (int k2 = 0; k2 < 32; ++k2) {
                float2 v = __half22float2(xr[k2]);
                acc += v.x * Wl[(k2 * 2 + 0) * 64 + lane];
                acc += v.y * Wl[(k2 * 2 + 1) * 64 + lane];
            }
            hs[(size_t)i * 64 + lane] = __float2half(acc * dinv[i]);
        }
    }
}

// ---- small GEMM: h4[i] = (xh[i,:64] @ W[64,4]) * dinv[i] ----
__global__ __launch_bounds__(256) void k_gemm4(const __half* __restrict__ xh,
                                               const float* __restrict__ W,
                                               const float* __restrict__ dinv,
                                               float4* __restrict__ h4, int n) {
    __shared__ float Wl[256];
    for (int idx = threadIdx.x; idx < 256; idx += 256) Wl[idx] = W[idx];
    __syncthreads();
    int i = blockIdx.x * 256 + threadIdx.x;
    if (i >= n) return;
    const __half2* ar = (const __half2*)(xh + (size_t)i * 64);
    float a0 = 0.f, a1 = 0.f, a2 = 0.f, a3 = 0.f;
    #pragma unroll
    for (int k2 = 0; k2 < 32; ++k2) {
        float2 v = __half22float2(ar[k2]);
        int k = k2 * 2;
        a0 += v.x * Wl[k * 4 + 0] + v.y * Wl[(k + 1) * 4 + 0];
        a1 += v.x * Wl[k * 4 + 1] + v.y * Wl[(k + 1) * 4 + 1];
        a2 += v.x * Wl[k * 4 + 2] + v.y * Wl[(k + 1) * 4 + 2];
        a3 += v.x * Wl[k * 4 + 3] + v.y * Wl[(k + 1) * 4 + 3];
    }
    float di = dinv[i];
    h4[i] = make_float4(a0 * di, a1 * di, a2 * di, a3 * di);
}

// ------- agg 64-wide fp16: out[d,:] = relu((Σ hs[s,:] + hs[d,:])*dinv[d] + b) -------
// one wave per node, one lane per feature; fp32 accumulate; unroll 8.

__global__ __launch_bounds__(256) void k_agg64h(const __half* __restrict__ hs,
                                                const float* __restrict__ dinv,
                                                const int* __restrict__ row_start,
                                                const int* __restrict__ csr_src,
                                                const float* __restrict__ bias,
                                                __half* __restrict__ out, int n) {
    int gw = (int)((blockIdx.x * 256 + threadIdx.x) >> 6);
    int lane = threadIdx.x & 63;
    if (gw >= n) return;
    float acc = __half2float(hs[(size_t)gw * 64 + lane]);  // self (prescaled)
    int s = row_start[gw], e = row_start[gw + 1];
    int slot = s;
    for (; slot + 8 <= e; slot += 8) {
        int i0 = csr_src[slot + 0], i1 = csr_src[slot + 1];
        int i2 = csr_src[slot + 2], i3 = csr_src[slot + 3];
        int i4 = csr_src[slot + 4], i5 = csr_src[slot + 5];
        int i6 = csr_src[slot + 6], i7 = csr_src[slot + 7];
        float v0 = __half2float(hs[(size_t)i0 * 64 + lane]);
        float v1 = __half2float(hs[(size_t)i1 * 64 + lane]);
        float v2 = __half2float(hs[(size_t)i2 * 64 + lane]);
        float v3 = __half2float(hs[(size_t)i3 * 64 + lane]);
        float v4 = __half2float(hs[(size_t)i4 * 64 + lane]);
        float v5 = __half2float(hs[(size_t)i5 * 64 + lane]);
        float v6 = __half2float(hs[(size_t)i6 * 64 + lane]);
        float v7 = __half2float(hs[(size_t)i7 * 64 + lane]);
        acc += ((v0 + v1) + (v2 + v3)) + ((v4 + v5) + (v6 + v7));
    }
    for (; slot < e; ++slot)
        acc += __half2float(hs[(size_t)csr_src[slot] * 64 + lane]);
    acc = acc * dinv[gw] + bias[lane];
    out[(size_t)gw * 64 + lane] = __float2half(fmaxf(acc, 0.f));
}

// ------- agg 4-wide (final): z[d] = (Σ h4[s] + h4[d])*dinv[d] + b3 -------

__global__ __launch_bounds__(256) void k_agg4(const float4* __restrict__ h4,
                                              const float* __restrict__ dinv,
                                              const int* __restrict__ row_start,
                                              const int* __restrict__ csr_src,
                                              const float* __restrict__ b3,
                                              float4* __restrict__ z, int n) {
    int i = blockIdx.x * 256 + threadIdx.x;
    if (i >= n) return;
    float4 self = h4[i];
    float a0 = self.x, a1 = self.y, a2 = self.z, a3 = self.w;
    int s = row_start[i], e = row_start[i + 1];
    int slot = s;
    for (; slot + 4 <= e; slot += 4) {
        int s0 = csr_src[slot], s1 = csr_src[slot + 1];
        int s2 = csr_src[slot + 2], s3 = csr_src[slot + 3];
        float4 v0 = h4[s0], v1 = h4[s1], v2 = h4[s2], v3 = h4[s3];
        a0 += v0.x + v1.x + v2.x + v3.x;
        a1 += v0.y + v1.y + v2.y + v3.y;
        a2 += v0.z + v1.z + v2.z + v3.z;
        a3 += v0.w + v1.w + v2.w + v3.w;
    }
    for (; slot < e; ++slot) {
        float4 v = h4[csr_src[slot]];
        a0 += v.x; a1 += v.y; a2 += v.z; a3 += v.w;
    }
    float di = dinv[i];
    z[i] = make_float4(a0 * di + b3[0], a1 * di + b3[1],
                       a2 * di + b3[2], a3 * di + b3[3]);
}

// ---------------- softmax over node axis (per column, C=4) ----------------

__device__ inline unsigned encf(float f) {
    unsigned u = __float_as_uint(f);
    return (u & 0x80000000u) ? ~u : (u | 0x80000000u);
}
__device__ inline float decf(unsigned e) {
    return (e & 0x80000000u) ? __uint_as_float(e & 0x7FFFFFFFu) : __uint_as_float(~e);
}

__global__ __launch_bounds__(256) void k_max(const float4* __restrict__ z,
                                             unsigned* __restrict__ gmax, int n) {
    float m0 = -FLT_MAX, m1 = -FLT_MAX, m2 = -FLT_MAX, m3 = -FLT_MAX;
    for (int i = blockIdx.x * 256 + threadIdx.x; i < n; i += gridDim.x * 256) {
        float4 v = z[i];
        m0 = fmaxf(m0, v.x); m1 = fmaxf(m1, v.y);
        m2 = fmaxf(m2, v.z); m3 = fmaxf(m3, v.w);
    }
    #pragma unroll
    for (int off = 32; off; off >>= 1) {
        m0 = fmaxf(m0, __shfl_xor(m0, off));
        m1 = fmaxf(m1, __shfl_xor(m1, off));
        m2 = fmaxf(m2, __shfl_xor(m2, off));
        m3 = fmaxf(m3, __shfl_xor(m3, off));
    }
    if ((threadIdx.x & 63) == 0) {
        atomicMax(&gmax[0], encf(m0));
        atomicMax(&gmax[1], encf(m1));
        atomicMax(&gmax[2], encf(m2));
        atomicMax(&gmax[3], encf(m3));
    }
}

__global__ __launch_bounds__(256) void k_exp(const float4* __restrict__ z,
                                             float4* __restrict__ out,
                                             const unsigned* __restrict__ gmax,
                                             float* __restrict__ gsum, int n) {
    float M0 = decf(gmax[0]), M1 = decf(gmax[1]), M2 = decf(gmax[2]), M3 = decf(gmax[3]);
    float s0 = 0.f, s1 = 0.f, s2 = 0.f, s3 = 0.f;
    for (int i = blockIdx.x * 256 + threadIdx.x; i < n; i += gridDim.x * 256) {
        float4 v = z[i];
        float4 e;
        e.x = expf(v.x - M0); e.y = expf(v.y - M1);
        e.z = expf(v.z - M2); e.w = expf(v.w - M3);
        out[i] = e;
        s0 += e.x; s1 += e.y; s2 += e.z; s3 += e.w;
    }
    #pragma unroll
    for (int off = 32; off; off >>= 1) {
        s0 += __shfl_xor(s0, off);
        s1 += __shfl_xor(s1, off);
        s2 += __shfl_xor(s2, off);
        s3 += __shfl_xor(s3, off);
    }
    if ((threadIdx.x & 63) == 0) {
        atomicAdd(&gsum[0], s0);
        atomicAdd(&gsum[1], s1);
        atomicAdd(&gsum[2], s2);
        atomicAdd(&gsum[3], s3);
    }
}

__global__ __launch_bounds__(256) void k_norm(float4* __restrict__ out,
                                              const float* __restrict__ gsum, int n) {
    float r0 = 1.f / gsum[0], r1 = 1.f / gsum[1], r2 = 1.f / gsum[2], r3 = 1.f / gsum[3];
    for (int i = blockIdx.x * 256 + threadIdx.x; i < n; i += gridDim.x * 256) {
        float4 v = out[i];
        v.x *= r0; v.y *= r1; v.z *= r2; v.w *= r3;
        out[i] = v;
    }
}

// ---------------------------------------------------------------------------

extern "C" void kernel_launch(void* const* d_in, const int* in_sizes, int n_in,
                              void* d_out, int out_size, void* d_ws, size_t ws_size,
                              hipStream_t stream) {
    const float* x0 = (const float*)d_in[0];
    const int* ei = (const int*)d_in[1];
    const float* W1 = (const float*)d_in[2];
    const float* b1 = (const float*)d_in[3];
    const float* W2 = (const float*)d_in[4];
    const float* b2 = (const float*)d_in[5];
    const float* W3 = (const float*)d_in[6];
    const float* b3 = (const float*)d_in[7];

    const int n = in_sizes[0] / 128;   // 50000
    const int E = in_sizes[1] / 2;     // 1600000
    const int* src = ei;
    const int* dst = ei + E;

    char* ws = (char*)d_ws;
    size_t off = 0;
    auto alloc = [&](size_t bytes) -> void* {
        void* p = (void*)(ws + off);
        off = (off + bytes + 255) & ~(size_t)255;
        return p;
    };

    // zeroed region first (deg, cursor, gmax, gsum)
    unsigned* deg    = (unsigned*)alloc((size_t)n * 4);
    unsigned* cursor = (unsigned*)alloc((size_t)n * 4);
    unsigned* gmax   = (unsigned*)alloc(16);
    float*    gsum   = (float*)alloc(16);
    size_t zero_bytes = off;

    float* dinv      = (float*)alloc((size_t)n * 4);
    int*   row_start = (int*)alloc((size_t)(n + 1) * 4);
    unsigned* bsum   = (unsigned*)alloc(1024 * 4);
    int*   csr_src   = (int*)alloc((size_t)E * 4);
    __half* hbuf     = (__half*)alloc((size_t)n * 64 * 2);
    __half* xbuf     = (__half*)alloc((size_t)n * 64 * 2);
    float4* h4buf    = (float4*)alloc((size_t)n * 16);
    float4* zbuf     = (float4*)alloc((size_t)n * 16);

    hipMemsetAsync(deg, 0, zero_bytes, stream);

    const int nbE = (E + 255) / 256;
    const int nbN = (n + 255) / 256;

    // CSR build
    k_count<<<nbE, 256, 0, stream>>>(dst, deg, E);
    k_dinv<<<nbN, 256, 0, stream>>>(deg, dinv, n);
    k_scan1<<<nbN, 256, 0, stream>>>(deg, row_start, bsum, n);
    k_scan2<<<1, 256, 0, stream>>>(bsum, row_start, nbN, n);
    k_scan3<<<nbN, 256, 0, stream>>>(row_start, bsum, n);
    k_fill<<<nbE, 256, 0, stream>>>(src, dst, row_start, cursor, csr_src, E);

    const int nbG = (n + 63) / 64;        // gemm blocks (64 nodes/block)
    const int nbA = (n * 64 + 255) / 256; // agg blocks (wave per node)

    // layer 1: 128 -> 64 (fp32 input)
    k_gemm64_f32<<<nbG, 256, 0, stream>>>(x0, W1, dinv, hbuf, n);
    k_agg64h<<<nbA, 256, 0, stream>>>(hbuf, dinv, row_start, csr_src, b1, xbuf, n);

    // layers 2..8: 64 -> 64, shared W2 (fp16 activations)
    for (int l = 0; l < 7; ++l) {
        k_gemm64_f16<<<nbG, 256, 0, stream>>>(xbuf, W2, dinv, hbuf, n);
        k_agg64h<<<nbA, 256, 0, stream>>>(hbuf, dinv, row_start, csr_src, b2, xbuf, n);
    }

    // layer 9: gemm to 4 features first, then 4-wide agg (fp32)
    k_gemm4<<<nbN, 256, 0, stream>>>(xbuf, W3, dinv, h4buf, n);
    k_agg4<<<nbN, 256, 0, stream>>>(h4buf, dinv, row_start, csr_src, b3, zbuf, n);

    // softmax over node axis
    k_max<<<256, 256, 0, stream>>>(zbuf, gmax, n);
    k_exp<<<256, 256, 0, stream>>>(zbuf, (float4*)d_out, gmax, gsum, n);
    k_norm<<<256, 256, 0, stream>>>((float4*)d_out, gsum, n);
}

// Round 7
// 899.359 us; speedup vs baseline: 1.4043x; 1.0962x over previous
//
#include <hip/hip_runtime.h>
#include <hip/hip_fp16.h>
#include <math.h>
#include <float.h>

// ---------------------------------------------------------------------------
// GCN on MI355X. N=50000, E=1.6M, widths 128 -> 64 (x8) -> 4.
// CSR (dst-sorted, src only) built per call with XCD-partitioned count/fill
// (each partition handles a contiguous dst range -> csr lines written by one
// XCD's L2 only -> no write amplification). dinv folded into GEMM epilogue
// and agg epilogue. Activations fp16 (fp32 accumulate). Final layer: GEMM to
// 4 features then 4-wide agg. Softmax over node axis.
// ---------------------------------------------------------------------------

#define NPART 8
#define BPP   104   // blocks per partition for count/fill

// ---------------- degree / CSR build (XCD-partitioned) ----------------

__global__ __launch_bounds__(256) void k_count(const int* __restrict__ dst,
                                               unsigned* __restrict__ deg,
                                               int E, int chunk) {
    int part = blockIdx.x & (NPART - 1);
    int q = blockIdx.x >> 3;
    int lo = part * chunk, hi = lo + chunk;
    for (int e = q * 256 + threadIdx.x; e < E; e += 256 * BPP) {
        int d = dst[e];
        if (d >= lo && d < hi) atomicAdd(&deg[d], 1u);
    }
}

__global__ __launch_bounds__(256) void k_dinv(const unsigned* __restrict__ deg,
                                              float* __restrict__ dinv, int n) {
    int i = blockIdx.x * 256 + threadIdx.x;
    if (i < n) dinv[i] = rsqrtf(1.0f + (float)deg[i]);
}

__global__ __launch_bounds__(256) void k_scan1(const unsigned* __restrict__ deg,
                                               int* __restrict__ row_start,
                                               unsigned* __restrict__ bsum, int n) {
    __shared__ unsigned t[256];
    int i = blockIdx.x * 256 + threadIdx.x;
    unsigned v = (i < n) ? deg[i] : 0u;
    t[threadIdx.x] = v;
    __syncthreads();
    #pragma unroll
    for (int off = 1; off < 256; off <<= 1) {
        unsigned u = (threadIdx.x >= (unsigned)off) ? t[threadIdx.x - off] : 0u;
        __syncthreads();
        t[threadIdx.x] += u;
        __syncthreads();
    }
    if (i < n) row_start[i] = (int)(t[threadIdx.x] - v);
    if (threadIdx.x == 255) bsum[blockIdx.x] = t[255];
}

__global__ __launch_bounds__(256) void k_scan2(unsigned* __restrict__ bsum,
                                               int* __restrict__ row_start,
                                               int nb, int n) {
    __shared__ unsigned t[256];
    unsigned v = (threadIdx.x < (unsigned)nb) ? bsum[threadIdx.x] : 0u;
    t[threadIdx.x] = v;
    __syncthreads();
    #pragma unroll
    for (int off = 1; off < 256; off <<= 1) {
        unsigned u = (threadIdx.x >= (unsigned)off) ? t[threadIdx.x - off] : 0u;
        __syncthreads();
        t[threadIdx.x] += u;
        __syncthreads();
    }
    if (threadIdx.x < (unsigned)nb) bsum[threadIdx.x] = t[threadIdx.x] - v;
    if (threadIdx.x == 255) row_start[n] = (int)t[255];
}

__global__ __launch_bounds__(256) void k_scan3(int* __restrict__ row_start,
                                               const unsigned* __restrict__ bsum, int n) {
    int i = blockIdx.x * 256 + threadIdx.x;
    if (i < n) row_start[i] += (int)bsum[blockIdx.x];
}

__global__ __launch_bounds__(256) void k_fill(const int* __restrict__ src,
                                              const int* __restrict__ dst,
                                              const int* __restrict__ row_start,
                                              unsigned* __restrict__ cursor,
                                              int* __restrict__ csr_src,
                                              int E, int chunk) {
    int part = blockIdx.x & (NPART - 1);
    int q = blockIdx.x >> 3;
    int lo = part * chunk, hi = lo + chunk;
    for (int e = q * 256 + threadIdx.x; e < E; e += 256 * BPP) {
        int d = dst[e];
        if (d >= lo && d < hi) {
            int s = src[e];
            unsigned pos = atomicAdd(&cursor[d], 1u);
            csr_src[row_start[d] + (int)pos] = s;
        }
    }
}

// ---- GEMM layer1: hs[i,:] = half((x[i,:128] @ W) * dinv[i]) ----

__global__ __launch_bounds__(256) void k_gemm64_f32(const float* __restrict__ x,
                                                    const float* __restrict__ W,
                                                    const float* __restrict__ dinv,
                                                    __half* __restrict__ hs, int n) {
    __shared__ float Wl[128 * 64];
    for (int idx = threadIdx.x; idx < 128 * 64; idx += 256) Wl[idx] = W[idx];
    __syncthreads();
    int wave = threadIdx.x >> 6, lane = threadIdx.x & 63;
    int base = blockIdx.x * 64 + wave * 16;
    for (int it = 0; it < 16; ++it) {
        int i = base + it;
        if (i < n) {
            const float4* xr = (const float4*)(x + (size_t)i * 128);
            float acc = 0.f;
            #pragma unroll
            for (int k4 = 0; k4 < 32; ++k4) {
                float4 v = xr[k4];
                acc += v.x * Wl[(k4 * 4 + 0) * 64 + lane];
                acc += v.y * Wl[(k4 * 4 + 1) * 64 + lane];
                acc += v.z * Wl[(k4 * 4 + 2) * 64 + lane];
                acc += v.w * Wl[(k4 * 4 + 3) * 64 + lane];
            }
            hs[(size_t)i * 64 + lane] = __float2half(acc * dinv[i]);
        }
    }
}

// ---- GEMM layers 2..8: hs[i,:] = half((xh[i,:64] @ W) * dinv[i]) ----

__global__ __launch_bounds__(256) void k_gemm64_f16(const __half* __restrict__ xh,
                                                    const float* __restrict__ W,
                                                    const float* __restrict__ dinv,
                                                    __half* __restrict__ hs, int n) {
    __shared__ float Wl[64 * 64];
    for (int idx = threadIdx.x; idx < 64 * 64; idx += 256) Wl[idx] = W[idx];
    __syncthreads();
    int wave = threadIdx.x >> 6, lane = threadIdx.x & 63;
    int base = blockIdx.x * 64 + wave * 16;
    for (int it = 0; it < 16; ++it) {
        int i = base + it;
        if (i < n) {
            const __half2* xr = (const __half2*)(xh + (size_t)i * 64);
            float acc = 0.f;
            #pragma unroll
            for (int k2 = 0; k2 < 32; ++k2) {
                float2 v = __half22float2(xr[k2]);
                acc += v.x * Wl[(k2 * 2 + 0) * 64 + lane];
                acc += v.y * Wl[(k2 * 2 + 1) * 64 + lane];
            }
            hs[(size_t)i * 64 + lane] = __float2half(acc * dinv[i]);
        }
    }
}

// ---- small GEMM: h4[i] = (xh[i,:64] @ W[64,4]) * dinv[i] ----
__global__ __launch_bounds__(256) void k_gemm4(const __half* __restrict__ xh,
                                               const float* __restrict__ W,
                                               const float* __restrict__ dinv,
                                               float4* __restrict__ h4, int n) {
    __shared__ float Wl[256];
    for (int idx = threadIdx.x; idx < 256; idx += 256) Wl[idx] = W[idx];
    __syncthreads();
    int i = blockIdx.x * 256 + threadIdx.x;
    if (i >= n) return;
    const __half2* ar = (const __half2*)(xh + (size_t)i * 64);
    float a0 = 0.f, a1 = 0.f, a2 = 0.f, a3 = 0.f;
    #pragma unroll
    for (int k2 = 0; k2 < 32; ++k2) {
        float2 v = __half22float2(ar[k2]);
        int k = k2 * 2;
        a0 += v.x * Wl[k * 4 + 0] + v.y * Wl[(k + 1) * 4 + 0];
        a1 += v.x * Wl[k * 4 + 1] + v.y * Wl[(k + 1) * 4 + 1];
        a2 += v.x * Wl[k * 4 + 2] + v.y * Wl[(k + 1) * 4 + 2];
        a3 += v.x * Wl[k * 4 + 3] + v.y * Wl[(k + 1) * 4 + 3];
    }
    float di = dinv[i];
    h4[i] = make_float4(a0 * di, a1 * di, a2 * di, a3 * di);
}

// ------- agg 64-wide fp16: out[d,:] = relu((Σ hs[s,:] + hs[d,:])*dinv[d] + b) -------
// one wave per node, one lane per feature; fp32 accumulate; unroll 16.

__global__ __launch_bounds__(256) void k_agg64h(const __half* __restrict__ hs,
                                                const float* __restrict__ dinv,
                                                const int* __restrict__ row_start,
                                                const int* __restrict__ csr_src,
                                                const float* __restrict__ bias,
                                                __half* __restrict__ out, int n) {
    int gw = (int)((blockIdx.x * 256 + threadIdx.x) >> 6);
    int lane = threadIdx.x & 63;
    if (gw >= n) return;
    float acc = __half2float(hs[(size_t)gw * 64 + lane]);  // self (prescaled)
    int s = row_start[gw], e = row_start[gw + 1];
    int slot = s;
    for (; slot + 16 <= e; slot += 16) {
        int idx[16];
        #pragma unroll
        for (int j = 0; j < 16; ++j) idx[j] = csr_src[slot + j];
        float v[16];
        #pragma unroll
        for (int j = 0; j < 16; ++j) v[j] = __half2float(hs[(size_t)idx[j] * 64 + lane]);
        float t0 = ((v[0] + v[1]) + (v[2] + v[3])) + ((v[4] + v[5]) + (v[6] + v[7]));
        float t1 = ((v[8] + v[9]) + (v[10] + v[11])) + ((v[12] + v[13]) + (v[14] + v[15]));
        acc += t0 + t1;
    }
    for (; slot + 4 <= e; slot += 4) {
        int i0 = csr_src[slot + 0], i1 = csr_src[slot + 1];
        int i2 = csr_src[slot + 2], i3 = csr_src[slot + 3];
        float v0 = __half2float(hs[(size_t)i0 * 64 + lane]);
        float v1 = __half2float(hs[(size_t)i1 * 64 + lane]);
        float v2 = __half2float(hs[(size_t)i2 * 64 + lane]);
        float v3 = __half2float(hs[(size_t)i3 * 64 + lane]);
        acc += (v0 + v1) + (v2 + v3);
    }
    for (; slot < e; ++slot)
        acc += __half2float(hs[(size_t)csr_src[slot] * 64 + lane]);
    acc = acc * dinv[gw] + bias[lane];
    out[(size_t)gw * 64 + lane] = __float2half(fmaxf(acc, 0.f));
}

// ------- agg 4-wide (final): z[d] = (Σ h4[s] + h4[d])*dinv[d] + b3 -------

__global__ __launch_bounds__(256) void k_agg4(const float4* __restrict__ h4,
                                              const float* __restrict__ dinv,
                                              const int* __restrict__ row_start,
                                              const int* __restrict__ csr_src,
                                              const float* __restrict__ b3,
                                              float4* __restrict__ z, int n) {
    int i = blockIdx.x * 256 + threadIdx.x;
    if (i >= n) return;
    float4 self = h4[i];
    float a0 = self.x, a1 = self.y, a2 = self.z, a3 = self.w;
    int s = row_start[i], e = row_start[i + 1];
    int slot = s;
    for (; slot + 4 <= e; slot += 4) {
        int s0 = csr_src[slot], s1 = csr_src[slot + 1];
        int s2 = csr_src[slot + 2], s3 = csr_src[slot + 3];
        float4 v0 = h4[s0], v1 = h4[s1], v2 = h4[s2], v3 = h4[s3];
        a0 += v0.x + v1.x + v2.x + v3.x;
        a1 += v0.y + v1.y + v2.y + v3.y;
        a2 += v0.z + v1.z + v2.z + v3.z;
        a3 += v0.w + v1.w + v2.w + v3.w;
    }
    for (; slot < e; ++slot) {
        float4 v = h4[csr_src[slot]];
        a0 += v.x; a1 += v.y; a2 += v.z; a3 += v.w;
    }
    float di = dinv[i];
    z[i] = make_float4(a0 * di + b3[0], a1 * di + b3[1],
                       a2 * di + b3[2], a3 * di + b3[3]);
}

// ---------------- softmax over node axis (per column, C=4) ----------------

__device__ inline unsigned encf(float f) {
    unsigned u = __float_as_uint(f);
    return (u & 0x80000000u) ? ~u : (u | 0x80000000u);
}
__device__ inline float decf(unsigned e) {
    return (e & 0x80000000u) ? __uint_as_float(e & 0x7FFFFFFFu) : __uint_as_float(~e);
}

__global__ __launch_bounds__(256) void k_max(const float4* __restrict__ z,
                                             unsigned* __restrict__ gmax, int n) {
    float m0 = -FLT_MAX, m1 = -FLT_MAX, m2 = -FLT_MAX, m3 = -FLT_MAX;
    for (int i = blockIdx.x * 256 + threadIdx.x; i < n; i += gridDim.x * 256) {
        float4 v = z[i];
        m0 = fmaxf(m0, v.x); m1 = fmaxf(m1, v.y);
        m2 = fmaxf(m2, v.z); m3 = fmaxf(m3, v.w);
    }
    #pragma unroll
    for (int off = 32; off; off >>= 1) {
        m0 = fmaxf(m0, __shfl_xor(m0, off));
        m1 = fmaxf(m1, __shfl_xor(m1, off));
        m2 = fmaxf(m2, __shfl_xor(m2, off));
        m3 = fmaxf(m3, __shfl_xor(m3, off));
    }
    if ((threadIdx.x & 63) == 0) {
        atomicMax(&gmax[0], encf(m0));
        atomicMax(&gmax[1], encf(m1));
        atomicMax(&gmax[2], encf(m2));
        atomicMax(&gmax[3], encf(m3));
    }
}

__global__ __launch_bounds__(256) void k_exp(const float4* __restrict__ z,
                                             float4* __restrict__ out,
                                             const unsigned* __restrict__ gmax,
                                             float* __restrict__ gsum, int n) {
    float M0 = decf(gmax[0]), M1 = decf(gmax[1]), M2 = decf(gmax[2]), M3 = decf(gmax[3]);
    float s0 = 0.f, s1 = 0.f, s2 = 0.f, s3 = 0.f;
    for (int i = blockIdx.x * 256 + threadIdx.x; i < n; i += gridDim.x * 256) {
        float4 v = z[i];
        float4 e;
        e.x = expf(v.x - M0); e.y = expf(v.y - M1);
        e.z = expf(v.z - M2); e.w = expf(v.w - M3);
        out[i] = e;
        s0 += e.x; s1 += e.y; s2 += e.z; s3 += e.w;
    }
    #pragma unroll
    for (int off = 32; off; off >>= 1) {
        s0 += __shfl_xor(s0, off);
        s1 += __shfl_xor(s1, off);
        s2 += __shfl_xor(s2, off);
        s3 += __shfl_xor(s3, off);
    }
    if ((threadIdx.x & 63) == 0) {
        atomicAdd(&gsum[0], s0);
        atomicAdd(&gsum[1], s1);
        atomicAdd(&gsum[2], s2);
        atomicAdd(&gsum[3], s3);
    }
}

__global__ __launch_bounds__(256) void k_norm(float4* __restrict__ out,
                                              const float* __restrict__ gsum, int n) {
    float r0 = 1.f / gsum[0], r1 = 1.f / gsum[1], r2 = 1.f / gsum[2], r3 = 1.f / gsum[3];
    for (int i = blockIdx.x * 256 + threadIdx.x; i < n; i += gridDim.x * 256) {
        float4 v = out[i];
        v.x *= r0; v.y *= r1; v.z *= r2; v.w *= r3;
        out[i] = v;
    }
}

// ---------------------------------------------------------------------------

extern "C" void kernel_launch(void* const* d_in, const int* in_sizes, int n_in,
                              void* d_out, int out_size, void* d_ws, size_t ws_size,
                              hipStream_t stream) {
    const float* x0 = (const float*)d_in[0];
    const int* ei = (const int*)d_in[1];
    const float* W1 = (const float*)d_in[2];
    const float* b1 = (const float*)d_in[3];
    const float* W2 = (const float*)d_in[4];
    const float* b2 = (const float*)d_in[5];
    const float* W3 = (const float*)d_in[6];
    const float* b3 = (const float*)d_in[7];

    const int n = in_sizes[0] / 128;   // 50000
    const int E = in_sizes[1] / 2;     // 1600000
    const int* src = ei;
    const int* dst = ei + E;
    const int chunk = (n + NPART - 1) / NPART;

    char* ws = (char*)d_ws;
    size_t off = 0;
    auto alloc = [&](size_t bytes) -> void* {
        void* p = (void*)(ws + off);
        off = (off + bytes + 255) & ~(size_t)255;
        return p;
    };

    // zeroed region first (deg, cursor, gmax, gsum)
    unsigned* deg    = (unsigned*)alloc((size_t)n * 4);
    unsigned* cursor = (unsigned*)alloc((size_t)n * 4);
    unsigned* gmax   = (unsigned*)alloc(16);
    float*    gsum   = (float*)alloc(16);
    size_t zero_bytes = off;

    float* dinv      = (float*)alloc((size_t)n * 4);
    int*   row_start = (int*)alloc((size_t)(n + 1) * 4);
    unsigned* bsum   = (unsigned*)alloc(1024 * 4);
    int*   csr_src   = (int*)alloc((size_t)E * 4);
    __half* hbuf     = (__half*)alloc((size_t)n * 64 * 2);
    __half* xbuf     = (__half*)alloc((size_t)n * 64 * 2);
    float4* h4buf    = (float4*)alloc((size_t)n * 16);
    float4* zbuf     = (float4*)alloc((size_t)n * 16);

    hipMemsetAsync(deg, 0, zero_bytes, stream);

    const int nbN = (n + 255) / 256;

    // CSR build (count/fill XCD-partitioned by dst range)
    k_count<<<NPART * BPP, 256, 0, stream>>>(dst, deg, E, chunk);
    k_dinv<<<nbN, 256, 0, stream>>>(deg, dinv, n);
    k_scan1<<<nbN, 256, 0, stream>>>(deg, row_start, bsum, n);
    k_scan2<<<1, 256, 0, stream>>>(bsum, row_start, nbN, n);
    k_scan3<<<nbN, 256, 0, stream>>>(row_start, bsum, n);
    k_fill<<<NPART * BPP, 256, 0, stream>>>(src, dst, row_start, cursor, csr_src, E, chunk);

    const int nbG = (n + 63) / 64;        // gemm blocks (64 nodes/block)
    const int nbA = (n * 64 + 255) / 256; // agg blocks (wave per node)

    // layer 1: 128 -> 64 (fp32 input)
    k_gemm64_f32<<<nbG, 256, 0, stream>>>(x0, W1, dinv, hbuf, n);
    k_agg64h<<<nbA, 256, 0, stream>>>(hbuf, dinv, row_start, csr_src, b1, xbuf, n);

    // layers 2..8: 64 -> 64, shared W2 (fp16 activations)
    for (int l = 0; l < 7; ++l) {
        k_gemm64_f16<<<nbG, 256, 0, stream>>>(xbuf, W2, dinv, hbuf, n);
        k_agg64h<<<nbA, 256, 0, stream>>>(hbuf, dinv, row_start, csr_src, b2, xbuf, n);
    }

    // layer 9: gemm to 4 features first, then 4-wide agg (fp32)
    k_gemm4<<<nbN, 256, 0, stream>>>(xbuf, W3, dinv, h4buf, n);
    k_agg4<<<nbN, 256, 0, stream>>>(h4buf, dinv, row_start, csr_src, b3, zbuf, n);

    // softmax over node axis
    k_max<<<256, 256, 0, stream>>>(zbuf, gmax, n);
    k_exp<<<256, 256, 0, stream>>>(zbuf, (float4*)d_out, gmax, gsum, n);
    k_norm<<<256, 256, 0, stream>>>((float4*)d_out, gsum, n);
}